// Round 13
// baseline (662.643 us; speedup 1.0000x reference)
//
#include <hip/hip_runtime.h>

#define D      12
#define ASTR   13
#define LOGNPB 7
#define NPB    128
#define CAPBF  5120
#define CAPF   9216
#define EPB    8192
#define ABLK   256
#define SBLK   256
#define CBLK   256
#define SPLIT  2

#define SWZ(p) ((p) ^ (((p) >> 5) & 31))

static __device__ __forceinline__ unsigned f2bf(float f) {
    union { float f; unsigned u; } v; v.f = f;
    unsigned r = v.u + 0x7FFFu + ((v.u >> 16) & 1u);
    return r >> 16;
}
static __device__ __forceinline__ float bf_lo(unsigned u) {
    union { unsigned u; float f; } v; v.u = u << 16; return v.f;
}
static __device__ __forceinline__ float bf_hi(unsigned u) {
    union { unsigned u; float f; } v; v.u = u & 0xFFFF0000u; return v.f;
}
static __device__ __forceinline__ unsigned pk(float a, float b) {
    return f2bf(a) | (f2bf(b) << 16);
}

// ---------------- pass A (fused): bucket histogram + optional f32->bf16 convert ---
__global__ __launch_bounds__(ABLK) void passA_hist_cvt(
    const int* __restrict__ receivers, const float* __restrict__ edges,
    unsigned* __restrict__ bfw, long E, int nbuck, int* __restrict__ cnt)
{
    extern __shared__ int hist[];
    for (int i = threadIdx.x; i < nbuck; i += ABLK) hist[i] = 0;
    __syncthreads();
    const long e0 = (long)blockIdx.x * EPB;
    long e1 = e0 + EPB; if (e1 > E) e1 = E;

    for (long e = e0 + threadIdx.x; e < e1; e += ABLK) {
        int r = receivers[e];
        atomicAdd(&hist[r >> LOGNPB], 1);
    }

    if (bfw != nullptr) {
        for (long pe = e0 + 2L * threadIdx.x; pe < e1; pe += 2L * ABLK) {
            const float4* p = reinterpret_cast<const float4*>(edges + pe * D);
            float4 a0 = p[0], a1 = p[1], a2 = p[2];
            if (pe + 1 < e1) {
                float4 b0 = p[3], b1 = p[4], b2 = p[5];
                uint4 w0, w1, w2;
                w0.x = pk(a0.x, a0.y); w0.y = pk(a0.z, a0.w);
                w0.z = pk(a1.x, a1.y); w0.w = pk(a1.z, a1.w);
                w1.x = pk(a2.x, a2.y); w1.y = pk(a2.z, a2.w);
                w1.z = pk(b0.x, b0.y); w1.w = pk(b0.z, b0.w);
                w2.x = pk(b1.x, b1.y); w2.y = pk(b1.z, b1.w);
                w2.z = pk(b2.x, b2.y); w2.w = pk(b2.z, b2.w);
                uint4* dst = reinterpret_cast<uint4*>(bfw) + (pe >> 1) * 3;
                dst[0] = w0; dst[1] = w1; dst[2] = w2;
            } else {
                uint2* dst = reinterpret_cast<uint2*>(bfw) + pe * 3;
                dst[0] = make_uint2(pk(a0.x, a0.y), pk(a0.z, a0.w));
                dst[1] = make_uint2(pk(a1.x, a1.y), pk(a1.z, a1.w));
                dst[2] = make_uint2(pk(a2.x, a2.y), pk(a2.z, a2.w));
            }
        }
    }
    __syncthreads();
    int* row = cnt + (long)blockIdx.x * nbuck;
    for (int i = threadIdx.x; i < nbuck; i += ABLK) row[i] = hist[i];
}

__global__ __launch_bounds__(SBLK) void passS1_colscan(
    int* __restrict__ cnt, int nblk, int nbuck, int* __restrict__ totals)
{
    int b = blockIdx.x;
    int t = threadIdx.x;
    __shared__ int csum[SBLK];
    int per = (nblk + SBLK - 1) / SBLK;
    int i0 = t * per;
    int i1 = i0 + per; if (i1 > nblk) i1 = nblk;
    int s = 0;
    for (int i = i0; i < i1; ++i) s += cnt[(long)i * nbuck + b];
    csum[t] = s;
    __syncthreads();
    for (int off = 1; off < SBLK; off <<= 1) {
        int add = (t >= off) ? csum[t - off] : 0;
        __syncthreads();
        csum[t] += add;
        __syncthreads();
    }
    int run = csum[t] - s;
    for (int i = i0; i < i1; ++i) {
        long a = (long)i * nbuck + b;
        int tmp = cnt[a];
        cnt[a] = run;
        run += tmp;
    }
    if (t == SBLK - 1) totals[b] = csum[SBLK - 1];
}

__global__ __launch_bounds__(1024) void passS2_basescan(
    const int* __restrict__ totals, int* __restrict__ base, int nbuck)
{
    __shared__ int sh[1024];
    int t = threadIdx.x;
    int v = (t < nbuck) ? totals[t] : 0;
    sh[t] = v;
    __syncthreads();
    for (int off = 1; off < 1024; off <<= 1) {
        int add = (t >= off) ? sh[t - off] : 0;
        __syncthreads();
        sh[t] += add;
        __syncthreads();
    }
    if (t < nbuck) base[t] = sh[t] - v;
}

__global__ __launch_bounds__(ABLK) void passB_scatter(
    const int* __restrict__ receivers, long E, int nbuck,
    const int* __restrict__ cnt, const int* __restrict__ base,
    unsigned int* __restrict__ sorted)
{
    extern __shared__ int cur[];
    const int* row = cnt + (long)blockIdx.x * nbuck;
    for (int i = threadIdx.x; i < nbuck; i += ABLK) cur[i] = row[i] + base[i];
    __syncthreads();
    long e0 = (long)blockIdx.x * EPB;
    long e1 = e0 + EPB; if (e1 > E) e1 = E;
    for (long e = e0 + threadIdx.x; e < e1; e += ABLK) {
        int r = receivers[e];
        int b = r >> LOGNPB;
        int pos = atomicAdd(&cur[b], 1);
        sorted[pos] = ((unsigned)e << LOGNPB) | (unsigned)(r & (NPB - 1));
    }
}

__device__ __forceinline__ void build_weights(
    int t,
    const float* __restrict__ bn_scale, const float* __restrict__ bn_bias,
    const float* __restrict__ bn_mean,  const float* __restrict__ bn_var,
    const float* __restrict__ W1, const float* __restrict__ b1,
    const float* __restrict__ W2, const float* __restrict__ b2,
    float* sW1, float* sW2, float* sB1, float* sB2)
{
    if (t < D * D) {
        int d = t / D;
        float a = bn_scale[d] * rsqrtf(bn_var[d] + 1e-5f);
        sW1[t] = a * W1[t];
        sW2[t] = W2[t];
    }
    if (t < D) {
        float acc = b1[t];
        #pragma unroll
        for (int d = 0; d < D; ++d) {
            float a = bn_scale[d] * rsqrtf(bn_var[d] + 1e-5f);
            float c = bn_bias[d] - bn_mean[d] * a;
            acc += c * W1[d * D + t];
        }
        sB1[t] = acc;
        sB2[t] = b2[t];
    }
}

__device__ __forceinline__ void mlp12(
    const float x[D],
    const float* sW1, const float* sW2, const float* sB1, const float* sB2,
    float y[D])
{
    float h[D];
    #pragma unroll
    for (int j = 0; j < D; ++j) h[j] = sB1[j];
    #pragma unroll
    for (int d = 0; d < D; ++d) {
        float xd = x[d];
        #pragma unroll
        for (int j = 0; j < D; ++j) h[j] = fmaf(xd, sW1[d * D + j], h[j]);
    }
    #pragma unroll
    for (int j = 0; j < D; ++j) h[j] = fmaxf(h[j], 0.f);
    #pragma unroll
    for (int j = 0; j < D; ++j) y[j] = sB2[j];
    #pragma unroll
    for (int d = 0; d < D; ++d) {
        float hd = h[d];
        #pragma unroll
        for (int j = 0; j < D; ++j) y[j] = fmaf(hd, sW2[d * D + j], y[j]);
    }
}

// ---------------- tier-1 pass C: dual-edge shared-weight-read MLP ----------------
__global__ __launch_bounds__(CBLK) void passC_bf(
    const uint2* __restrict__ bfrows,
    const unsigned int* __restrict__ sortedG,
    const int* __restrict__ base, const int* __restrict__ totals,
    const float* __restrict__ bn_scale, const float* __restrict__ bn_bias,
    const float* __restrict__ bn_mean,  const float* __restrict__ bn_var,
    const float* __restrict__ W1, const float* __restrict__ b1,
    const float* __restrict__ W2, const float* __restrict__ b2,
    float* __restrict__ part, float* __restrict__ out,
    long total, long slab)
{
    __shared__ float sW1[D * D], sW2[D * D], sB1[D], sB2[D];
    __shared__ int hist[NPB];
    __shared__ int off[NPB + 1];
    __shared__ int cur[NPB];
    __shared__ unsigned sorted2[CAPBF];
    __shared__ float facc[NPB * ASTR];

    const int t = threadIdx.x;
    build_weights(t, bn_scale, bn_bias, bn_mean, bn_var, W1, b1, W2, b2,
                  sW1, sW2, sB1, sB2);
    for (int i = t; i < NPB * ASTR; i += CBLK) facc[i] = 0.f;
    if (t < NPB) hist[t] = 0;
    __syncthreads();

    const int b = blockIdx.x;
    const int s = blockIdx.y;
    const int S = gridDim.y;
    const int s0 = base[b];
    const int n  = totals[b];
    const int chunk = (n + S - 1) / S;
    const int g0 = s * chunk;
    int g1 = g0 + chunk; if (g1 > n) g1 = n;
    const int ns = g1 - g0;
    const unsigned* __restrict__ src = sortedG + s0 + g0;

    if (ns > 0 && ns <= CAPBF) {
        for (int k = t; k < ns; k += CBLK)
            atomicAdd(&hist[src[k] & (NPB - 1)], 1);
        __syncthreads();

        int myh = (t < NPB) ? hist[t] : 0;
        if (t < NPB) off[t] = myh;
        __syncthreads();
        for (int d2 = 1; d2 < NPB; d2 <<= 1) {
            int add = 0;
            if (t < NPB && t >= d2) add = off[t - d2];
            __syncthreads();
            if (t < NPB) off[t] += add;
            __syncthreads();
        }
        if (t < NPB) cur[t] = off[t] - myh;
        __syncthreads();
        if (t < NPB) off[t] = cur[t];
        if (t == 0) off[NPB] = ns;
        __syncthreads();

        for (int k = t; k < ns; k += CBLK) {
            unsigned e = src[k];
            int pos = atomicAdd(&cur[e & (NPB - 1)], 1);
            sorted2[SWZ(pos)] = e >> LOGNPB;
        }
        __syncthreads();

        const int per = (ns + CBLK - 1) / CBLK;
        int k0 = t * per;
        int k1 = k0 + per; if (k1 > ns) k1 = ns;
        if (k0 < k1) {
            int cu = 0;
            while (off[cu + 1] <= k0) ++cu;
            int nodeEnd = off[cu + 1];

            float ac[D];
            #pragma unroll
            for (int j = 0; j < D; ++j) ac[j] = 0.f;

            const int kmax = k1 - 1;
            unsigned iA = sorted2[SWZ(k0)];
            unsigned iB = sorted2[SWZ((k0 + 1 <= kmax) ? k0 + 1 : kmax)];
            const uint2* pA = bfrows + (size_t)iA * 3;
            const uint2* pB = bfrows + (size_t)iB * 3;
            uint2 a0 = pA[0], a1 = pA[1], a2 = pA[2];
            uint2 c0 = pB[0], c1 = pB[1], c2 = pB[2];

            for (int k = k0; k < k1; k += 2) {
                int kn0 = (k + 2 <= kmax) ? k + 2 : kmax;
                int kn1 = (k + 3 <= kmax) ? k + 3 : kmax;
                unsigned jA = sorted2[SWZ(kn0)];
                unsigned jB = sorted2[SWZ(kn1)];
                const uint2* qA = bfrows + (size_t)jA * 3;
                const uint2* qB = bfrows + (size_t)jB * 3;
                uint2 na0 = qA[0], na1 = qA[1], na2 = qA[2];
                uint2 nb0 = qB[0], nb1 = qB[1], nb2 = qB[2];

                if (k >= nodeEnd) {
                    #pragma unroll
                    for (int j = 0; j < D; ++j) {
                        atomicAdd(&facc[cu * ASTR + j], ac[j]);
                        ac[j] = 0.f;
                    }
                    do { ++cu; } while (off[cu + 1] <= k);
                    nodeEnd = off[cu + 1];
                }
                const bool hasB = (k + 1 < k1);
                float x0[D] = {bf_lo(a0.x), bf_hi(a0.x), bf_lo(a0.y), bf_hi(a0.y),
                               bf_lo(a1.x), bf_hi(a1.x), bf_lo(a1.y), bf_hi(a1.y),
                               bf_lo(a2.x), bf_hi(a2.x), bf_lo(a2.y), bf_hi(a2.y)};
                if (hasB && (k + 1 < nodeEnd)) {
                    float x1[D] = {bf_lo(c0.x), bf_hi(c0.x), bf_lo(c0.y), bf_hi(c0.y),
                                   bf_lo(c1.x), bf_hi(c1.x), bf_lo(c1.y), bf_hi(c1.y),
                                   bf_lo(c2.x), bf_hi(c2.x), bf_lo(c2.y), bf_hi(c2.y)};
                    float h0[D], h1[D];
                    #pragma unroll
                    for (int j = 0; j < D; ++j) { float bj = sB1[j]; h0[j] = bj; h1[j] = bj; }
                    #pragma unroll
                    for (int d = 0; d < D; ++d) {
                        float xa = x0[d], xb = x1[d];
                        #pragma unroll
                        for (int j = 0; j < D; ++j) {
                            float w = sW1[d * D + j];
                            h0[j] = fmaf(xa, w, h0[j]);
                            h1[j] = fmaf(xb, w, h1[j]);
                        }
                    }
                    #pragma unroll
                    for (int j = 0; j < D; ++j) {
                        h0[j] = fmaxf(h0[j], 0.f);
                        h1[j] = fmaxf(h1[j], 0.f);
                    }
                    #pragma unroll
                    for (int d = 0; d < D; ++d) {
                        float ha = h0[d], hb = h1[d];
                        #pragma unroll
                        for (int j = 0; j < D; ++j) {
                            float w = sW2[d * D + j];
                            ac[j] = fmaf(ha, w, fmaf(hb, w, ac[j]));
                        }
                    }
                } else {
                    {
                        float h[D];
                        #pragma unroll
                        for (int j = 0; j < D; ++j) h[j] = sB1[j];
                        #pragma unroll
                        for (int d = 0; d < D; ++d) {
                            float xd = x0[d];
                            #pragma unroll
                            for (int j = 0; j < D; ++j) h[j] = fmaf(xd, sW1[d * D + j], h[j]);
                        }
                        #pragma unroll
                        for (int j = 0; j < D; ++j) h[j] = fmaxf(h[j], 0.f);
                        #pragma unroll
                        for (int d = 0; d < D; ++d) {
                            float hd = h[d];
                            #pragma unroll
                            for (int j = 0; j < D; ++j) ac[j] = fmaf(hd, sW2[d * D + j], ac[j]);
                        }
                    }
                    if (hasB) {
                        if (k + 1 >= nodeEnd) {
                            #pragma unroll
                            for (int j = 0; j < D; ++j) {
                                atomicAdd(&facc[cu * ASTR + j], ac[j]);
                                ac[j] = 0.f;
                            }
                            do { ++cu; } while (off[cu + 1] <= k + 1);
                            nodeEnd = off[cu + 1];
                        }
                        float x1[D] = {bf_lo(c0.x), bf_hi(c0.x), bf_lo(c0.y), bf_hi(c0.y),
                                       bf_lo(c1.x), bf_hi(c1.x), bf_lo(c1.y), bf_hi(c1.y),
                                       bf_lo(c2.x), bf_hi(c2.x), bf_lo(c2.y), bf_hi(c2.y)};
                        float h[D];
                        #pragma unroll
                        for (int j = 0; j < D; ++j) h[j] = sB1[j];
                        #pragma unroll
                        for (int d = 0; d < D; ++d) {
                            float xd = x1[d];
                            #pragma unroll
                            for (int j = 0; j < D; ++j) h[j] = fmaf(xd, sW1[d * D + j], h[j]);
                        }
                        #pragma unroll
                        for (int j = 0; j < D; ++j) h[j] = fmaxf(h[j], 0.f);
                        #pragma unroll
                        for (int d = 0; d < D; ++d) {
                            float hd = h[d];
                            #pragma unroll
                            for (int j = 0; j < D; ++j) ac[j] = fmaf(hd, sW2[d * D + j], ac[j]);
                        }
                    }
                }
                a0 = na0; a1 = na1; a2 = na2;
                c0 = nb0; c1 = nb1; c2 = nb2;
            }
            #pragma unroll
            for (int j = 0; j < D; ++j) atomicAdd(&facc[cu * ASTR + j], ac[j]);
        }
    } else if (ns > 0) {
        for (int k = t; k < ns; k += CBLK) {
            unsigned e = src[k];
            const uint2* rp = bfrows + (size_t)(e >> LOGNPB) * 3;
            uint2 r0 = rp[0], r1 = rp[1], r2 = rp[2];
            float x[D] = {bf_lo(r0.x), bf_hi(r0.x), bf_lo(r0.y), bf_hi(r0.y),
                          bf_lo(r1.x), bf_hi(r1.x), bf_lo(r1.y), bf_hi(r1.y),
                          bf_lo(r2.x), bf_hi(r2.x), bf_lo(r2.y), bf_hi(r2.y)};
            float y[D];
            mlp12(x, sW1, sW2, sB1, sB2, y);
            int rloc = (int)(e & (NPB - 1));
            #pragma unroll
            for (int j = 0; j < D; ++j) atomicAdd(&facc[rloc * ASTR + j], y[j]);
        }
    }
    __syncthreads();

    if (part != nullptr) {
        float* dst = part + (long)s * slab + (long)b * (NPB * D);
        for (int i = t; i < NPB * D; i += CBLK) {
            int node = i / D, j = i % D;
            dst[i] = facc[node * ASTR + j] + (float)hist[node] * sB2[j];
        }
    } else {
        long obase = (long)b * (NPB * D);
        long cnt_w = total - obase; if (cnt_w > NPB * D) cnt_w = NPB * D;
        for (long i = t; i < cnt_w; i += CBLK) {
            int node = (int)i / D, j = (int)i % D;
            out[obase + i] = facc[node * ASTR + j] + (float)hist[node] * sB2[j];
        }
    }
}

__global__ __launch_bounds__(CBLK) void reduce_partials(
    const float* __restrict__ part, float* __restrict__ out,
    long total4, long slab4, int S)
{
    long i = (long)blockIdx.x * CBLK + threadIdx.x;
    if (i >= total4) return;
    const float4* p = reinterpret_cast<const float4*>(part);
    float4 v = p[i];
    for (int s = 1; s < S; ++s) {
        float4 w = p[(long)s * slab4 + i];
        v.x += w.x; v.y += w.y; v.z += w.z; v.w += w.w;
    }
    reinterpret_cast<float4*>(out)[i] = v;
}

// ---------------- tier-2 pass C: r7 exact (f32 gather, no split) ----------------
__global__ __launch_bounds__(CBLK) void passC_f32(
    const float* __restrict__ edges,
    const unsigned int* __restrict__ sortedG,
    const int* __restrict__ base, const int* __restrict__ totals,
    const float* __restrict__ bn_scale, const float* __restrict__ bn_bias,
    const float* __restrict__ bn_mean,  const float* __restrict__ bn_var,
    const float* __restrict__ W1, const float* __restrict__ b1,
    const float* __restrict__ W2, const float* __restrict__ b2,
    float* __restrict__ out, long total)
{
    __shared__ float sW1[D * D], sW2[D * D], sB1[D], sB2[D];
    __shared__ int hist[NPB];
    __shared__ int off[NPB + 1];
    __shared__ int cur[NPB];
    __shared__ unsigned sorted2[CAPF];
    __shared__ float facc[NPB * ASTR];

    const int t = threadIdx.x;
    build_weights(t, bn_scale, bn_bias, bn_mean, bn_var, W1, b1, W2, b2,
                  sW1, sW2, sB1, sB2);
    for (int i = t; i < NPB * ASTR; i += CBLK) facc[i] = 0.f;
    if (t < NPB) hist[t] = 0;
    __syncthreads();

    const int b = blockIdx.x;
    const int s0 = base[b];
    const int n  = totals[b];

    if (n <= CAPF) {
        for (int k = t; k < n; k += CBLK)
            atomicAdd(&hist[sortedG[s0 + k] & (NPB - 1)], 1);
        __syncthreads();
        int myh = (t < NPB) ? hist[t] : 0;
        if (t < NPB) off[t] = myh;
        __syncthreads();
        for (int d2 = 1; d2 < NPB; d2 <<= 1) {
            int add = 0;
            if (t < NPB && t >= d2) add = off[t - d2];
            __syncthreads();
            if (t < NPB) off[t] += add;
            __syncthreads();
        }
        if (t < NPB) cur[t] = off[t] - myh;
        __syncthreads();
        if (t < NPB) off[t] = cur[t];
        if (t == 0) off[NPB] = n;
        __syncthreads();
        for (int k = t; k < n; k += CBLK) {
            unsigned e = sortedG[s0 + k];
            int pos = atomicAdd(&cur[e & (NPB - 1)], 1);
            sorted2[SWZ(pos)] = e >> LOGNPB;
        }
        __syncthreads();

        const int per = (n + CBLK - 1) / CBLK;
        int k0 = t * per;
        int k1 = k0 + per; if (k1 > n) k1 = n;
        if (k0 < k1) {
            int cu = 0;
            while (off[cu + 1] <= k0) ++cu;
            int nodeEnd = off[cu + 1];
            float ac[D];
            #pragma unroll
            for (int j = 0; j < D; ++j) ac[j] = 0.f;
            unsigned idx = sorted2[SWZ(k0)];
            const float4* p = reinterpret_cast<const float4*>(edges + (long)idx * D);
            float4 c0 = p[0], c1 = p[1], c2 = p[2];
            for (int k = k0; k < k1; ++k) {
                float4 n0 = c0, n1 = c1, n2 = c2;
                if (k + 1 < k1) {
                    unsigned ix = sorted2[SWZ(k + 1)];
                    const float4* q = reinterpret_cast<const float4*>(edges + (long)ix * D);
                    n0 = q[0]; n1 = q[1]; n2 = q[2];
                }
                if (k >= nodeEnd) {
                    #pragma unroll
                    for (int j = 0; j < D; ++j) {
                        atomicAdd(&facc[cu * ASTR + j], ac[j]);
                        ac[j] = 0.f;
                    }
                    do { ++cu; } while (off[cu + 1] <= k);
                    nodeEnd = off[cu + 1];
                }
                float x[D] = {c0.x, c0.y, c0.z, c0.w, c1.x, c1.y, c1.z, c1.w,
                              c2.x, c2.y, c2.z, c2.w};
                float y[D];
                mlp12(x, sW1, sW2, sB1, sB2, y);
                #pragma unroll
                for (int j = 0; j < D; ++j) ac[j] += y[j];
                c0 = n0; c1 = n1; c2 = n2;
            }
            #pragma unroll
            for (int j = 0; j < D; ++j) atomicAdd(&facc[cu * ASTR + j], ac[j]);
        }
    } else {
        for (int k = t; k < n; k += CBLK) {
            unsigned e = sortedG[s0 + k];
            const float4* p = reinterpret_cast<const float4*>(edges + (long)(e >> LOGNPB) * D);
            float4 c0 = p[0], c1 = p[1], c2 = p[2];
            float x[D] = {c0.x, c0.y, c0.z, c0.w, c1.x, c1.y, c1.z, c1.w,
                          c2.x, c2.y, c2.z, c2.w};
            float y[D];
            mlp12(x, sW1, sW2, sB1, sB2, y);
            int rloc = (int)(e & (NPB - 1));
            #pragma unroll
            for (int j = 0; j < D; ++j) atomicAdd(&facc[rloc * ASTR + j], y[j]);
        }
    }
    __syncthreads();

    long obase = (long)b * (NPB * D);
    long cnt_w = total - obase; if (cnt_w > NPB * D) cnt_w = NPB * D;
    for (long i = t; i < cnt_w; i += CBLK)
        out[obase + i] = facc[((int)i / D) * ASTR + ((int)i % D)];
}

#define EPT 4
__global__ __launch_bounds__(ABLK) void edge_mlp_scatter(
    const float* __restrict__ edges,
    const float* __restrict__ bn_scale, const float* __restrict__ bn_bias,
    const float* __restrict__ bn_mean,  const float* __restrict__ bn_var,
    const float* __restrict__ W1, const float* __restrict__ b1,
    const float* __restrict__ W2, const float* __restrict__ b2,
    const int* __restrict__ receivers, float* __restrict__ out, long E)
{
    __shared__ float sW1[D * D], sW2[D * D], sB1[D], sB2[D];
    const int t = threadIdx.x;
    build_weights(t, bn_scale, bn_bias, bn_mean, bn_var, W1, b1, W2, b2,
                  sW1, sW2, sB1, sB2);
    __syncthreads();
    const long basee = (long)blockIdx.x * (ABLK * EPT) + t;
    #pragma unroll
    for (int kk = 0; kk < EPT; ++kk) {
        long e = basee + (long)kk * ABLK;
        if (e >= E) continue;
        int r = receivers[e];
        const float4* p = reinterpret_cast<const float4*>(edges + e * D);
        float4 v0 = p[0], v1 = p[1], v2 = p[2];
        float x[D] = {v0.x, v0.y, v0.z, v0.w, v1.x, v1.y, v1.z, v1.w,
                      v2.x, v2.y, v2.z, v2.w};
        float y[D];
        mlp12(x, sW1, sW2, sB1, sB2, y);
        #pragma unroll
        for (int j = 0; j < D; ++j) atomicAdd(&out[(long)r * D + j], y[j]);
    }
}

extern "C" void kernel_launch(void* const* d_in, const int* in_sizes, int n_in,
                              void* d_out, int out_size, void* d_ws, size_t ws_size,
                              hipStream_t stream) {
    const float* edges     = (const float*)d_in[0];
    const float* bn_scale  = (const float*)d_in[1];
    const float* bn_bias   = (const float*)d_in[2];
    const float* bn_mean   = (const float*)d_in[3];
    const float* bn_var    = (const float*)d_in[4];
    const float* W1        = (const float*)d_in[5];
    const float* b1        = (const float*)d_in[6];
    const float* W2        = (const float*)d_in[7];
    const float* b2        = (const float*)d_in[8];
    const int*   receivers = (const int*)d_in[9];
    float*       out       = (float*)d_out;

    const long E = (long)in_sizes[0] / D;
    const int  N = out_size / D;

    const int  nbuck = (N + NPB - 1) >> LOGNPB;
    const long nblk  = (E + EPB - 1) / EPB;
    const size_t cntBytes  = (size_t)nblk * (size_t)nbuck * 4u;
    const size_t head      = cntBytes + 2u * (size_t)nbuck * 4u + 512u;
    const size_t bfBytes   = (size_t)E * 24u;
    const size_t slabBytes = (size_t)nbuck * (size_t)(NPB * D) * 4u;
    const size_t needT1 = head + (size_t)E * 4u + bfBytes + (size_t)SPLIT * slabBytes + 1024u;
    const size_t needT2 = head + (size_t)E * 4u;
    const long total = (long)N * D;

    const bool shapeOK = (nbuck <= 1024) && (E < (1L << 24));
    const size_t lds = (size_t)nbuck * 4u;

    if (shapeOK && ws_size >= needT1) {
        char* w = (char*)d_ws;
        int* cnt    = (int*)w;  w += cntBytes;
        int* totals = (int*)w;  w += (size_t)nbuck * 4u;
        int* basep  = (int*)w;  w += (size_t)nbuck * 4u;
        unsigned int* sortedG = (unsigned int*)w;  w += (size_t)E * 4u;
        unsigned* bfw = (unsigned*)(((uintptr_t)w + 255u) & ~(uintptr_t)255u);
        w = (char*)bfw + bfBytes;
        float* part = (float*)(((uintptr_t)w + 255u) & ~(uintptr_t)255u);

        passA_hist_cvt<<<dim3((unsigned)nblk), dim3(ABLK), lds, stream>>>(
            receivers, edges, bfw, E, nbuck, cnt);
        passS1_colscan<<<dim3((unsigned)nbuck), dim3(SBLK), 0, stream>>>(cnt, (int)nblk, nbuck, totals);
        passS2_basescan<<<dim3(1), dim3(1024), 0, stream>>>(totals, basep, nbuck);
        passB_scatter <<<dim3((unsigned)nblk), dim3(ABLK), lds, stream>>>(receivers, E, nbuck, cnt, basep, sortedG);

        const long slab = (long)nbuck * (NPB * D);
        passC_bf      <<<dim3((unsigned)nbuck, SPLIT), dim3(CBLK), 0, stream>>>(
            (const uint2*)bfw, sortedG, basep, totals,
            bn_scale, bn_bias, bn_mean, bn_var, W1, b1, W2, b2,
            part, out, total, slab);
        const long total4 = total / 4;
        const long rblocks = (total4 + CBLK - 1) / CBLK;
        reduce_partials<<<dim3((unsigned)rblocks), dim3(CBLK), 0, stream>>>(
            part, out, total4, slab / 4, SPLIT);
        return;
    }

    if (shapeOK && ws_size >= needT2) {
        char* w = (char*)d_ws;
        int* cnt    = (int*)w;  w += cntBytes;
        int* totals = (int*)w;  w += (size_t)nbuck * 4u;
        int* basep  = (int*)w;  w += (size_t)nbuck * 4u;
        unsigned int* sortedG = (unsigned int*)w;

        passA_hist_cvt<<<dim3((unsigned)nblk), dim3(ABLK), lds, stream>>>(
            receivers, edges, nullptr, E, nbuck, cnt);
        passS1_colscan<<<dim3((unsigned)nbuck), dim3(SBLK), 0, stream>>>(cnt, (int)nblk, nbuck, totals);
        passS2_basescan<<<dim3(1), dim3(1024), 0, stream>>>(totals, basep, nbuck);
        passB_scatter <<<dim3((unsigned)nblk), dim3(ABLK), lds, stream>>>(receivers, E, nbuck, cnt, basep, sortedG);
        passC_f32     <<<dim3((unsigned)nbuck), dim3(CBLK), 0, stream>>>(
            edges, sortedG, basep, totals,
            bn_scale, bn_bias, bn_mean, bn_var, W1, b1, W2, b2, out, total);
        return;
    }

    (void)hipMemsetAsync(d_out, 0, (size_t)out_size * sizeof(float), stream);
    const long blocks = (E + (long)(ABLK * EPT) - 1) / (long)(ABLK * EPT);
    edge_mlp_scatter<<<dim3((unsigned)blocks), dim3(ABLK), 0, stream>>>(
        edges, bn_scale, bn_bias, bn_mean, bn_var, W1, b1, W2, b2,
        receivers, out, E);
}

// Round 14
// 550.709 us; speedup vs baseline: 1.2033x; 1.2033x over previous
//
#include <hip/hip_runtime.h>

#define D      12
#define ASTR   13     // LDS acc stride (coprime with 32 banks)
#define LOGNPB 7
#define NPB    128    // nodes per bucket
#define CAPS   2944   // tier-1: max sub-range (bucket/SPLIT) in LDS (mean 2046)
#define CAPF   9216   // tier-2: max bucket in LDS
#define EPB    8192   // edges per block for passes A/B
#define ABLK   256
#define SBLK   256
#define CBLK   256
#define SPLIT  4      // blocks per bucket in tier-1 pass C

#define SWZ(p) ((p) ^ (((p) >> 5) & 31))

// ---- bf16 helpers (r6/r12-validated quantization; absmax 0.5 < 1.5 thr) ----
static __device__ __forceinline__ unsigned f2bf(float f) {
    union { float f; unsigned u; } v; v.f = f;
    unsigned r = v.u + 0x7FFFu + ((v.u >> 16) & 1u);   // RNE
    return r >> 16;
}
static __device__ __forceinline__ float bf_lo(unsigned u) {
    union { unsigned u; float f; } v; v.u = u << 16; return v.f;
}
static __device__ __forceinline__ float bf_hi(unsigned u) {
    union { unsigned u; float f; } v; v.u = u & 0xFFFF0000u; return v.f;
}
static __device__ __forceinline__ unsigned pk(float a, float b) {
    return f2bf(a) | (f2bf(b) << 16);
}

__device__ __forceinline__ void build_weights(
    int t,
    const float* __restrict__ bn_scale, const float* __restrict__ bn_bias,
    const float* __restrict__ bn_mean,  const float* __restrict__ bn_var,
    const float* __restrict__ W1, const float* __restrict__ b1,
    const float* __restrict__ W2, const float* __restrict__ b2,
    float* sW1, float* sW2, float* sB1, float* sB2)
{
    if (t < D * D) {
        int d = t / D;
        float a = bn_scale[d] * rsqrtf(bn_var[d] + 1e-5f);
        sW1[t] = a * W1[t];
        sW2[t] = W2[t];
    }
    if (t < D) {
        float acc = b1[t];
        #pragma unroll
        for (int d = 0; d < D; ++d) {
            float a = bn_scale[d] * rsqrtf(bn_var[d] + 1e-5f);
            float c = bn_bias[d] - bn_mean[d] * a;
            acc += c * W1[d * D + t];
        }
        sB1[t] = acc;
        sB2[t] = b2[t];
    }
}

__device__ __forceinline__ void mlp12(
    const float x[D],
    const float* sW1, const float* sW2, const float* sB1, const float* sB2,
    float y[D])
{
    float h[D];
    #pragma unroll
    for (int j = 0; j < D; ++j) h[j] = sB1[j];
    #pragma unroll
    for (int d = 0; d < D; ++d) {
        float xd = x[d];
        #pragma unroll
        for (int j = 0; j < D; ++j) h[j] = fmaf(xd, sW1[d * D + j], h[j]);
    }
    #pragma unroll
    for (int j = 0; j < D; ++j) h[j] = fmaxf(h[j], 0.f);
    #pragma unroll
    for (int j = 0; j < D; ++j) y[j] = sB2[j];
    #pragma unroll
    for (int d = 0; d < D; ++d) {
        float hd = h[d];
        #pragma unroll
        for (int j = 0; j < D; ++j) y[j] = fmaf(hd, sW2[d * D + j], y[j]);
    }
}

// ---------------- tier-1 pass A: stream edges, full MLP, write bf16 msg ----------
// Coalesced read (48B/row in order) + coalesced write (24B/row in order).
// The random access problem is thereby reduced to gathering 24B SUM-ONLY rows.
__global__ __launch_bounds__(ABLK) void passA_cvt_mlp(
    const int* __restrict__ receivers, const float* __restrict__ edges,
    unsigned* __restrict__ msg /* 6 u32 per edge */,
    long E, int nbuck, int* __restrict__ cnt,
    const float* __restrict__ bn_scale, const float* __restrict__ bn_bias,
    const float* __restrict__ bn_mean,  const float* __restrict__ bn_var,
    const float* __restrict__ W1, const float* __restrict__ b1,
    const float* __restrict__ W2, const float* __restrict__ b2)
{
    __shared__ float sW1[D * D], sW2[D * D], sB1[D], sB2[D];
    extern __shared__ int hist[];
    const int t = threadIdx.x;
    for (int i = t; i < nbuck; i += ABLK) hist[i] = 0;
    build_weights(t, bn_scale, bn_bias, bn_mean, bn_var, W1, b1, W2, b2,
                  sW1, sW2, sB1, sB2);
    __syncthreads();

    const long e0 = (long)blockIdx.x * EPB;
    long e1 = e0 + EPB; if (e1 > E) e1 = E;

    for (long e = e0 + t; e < e1; e += ABLK) {
        int r = receivers[e];
        atomicAdd(&hist[r >> LOGNPB], 1);

        const float4* p = reinterpret_cast<const float4*>(edges + e * D);
        float4 v0 = p[0], v1 = p[1], v2 = p[2];
        float x[D] = {v0.x, v0.y, v0.z, v0.w, v1.x, v1.y, v1.z, v1.w,
                      v2.x, v2.y, v2.z, v2.w};
        float y[D];
        mlp12(x, sW1, sW2, sB1, sB2, y);

        uint2* dst = reinterpret_cast<uint2*>(msg + (size_t)e * 6u);
        dst[0] = make_uint2(pk(y[0], y[1]),  pk(y[2], y[3]));
        dst[1] = make_uint2(pk(y[4], y[5]),  pk(y[6], y[7]));
        dst[2] = make_uint2(pk(y[8], y[9]),  pk(y[10], y[11]));
    }
    __syncthreads();
    int* row = cnt + (long)blockIdx.x * nbuck;
    for (int i = t; i < nbuck; i += ABLK) row[i] = hist[i];
}

// ---------------- pass A (tier-2): histogram only ----------------
__global__ __launch_bounds__(ABLK) void passA_hist(
    const int* __restrict__ receivers, long E, int nbuck,
    int* __restrict__ cnt)
{
    extern __shared__ int hist[];
    for (int i = threadIdx.x; i < nbuck; i += ABLK) hist[i] = 0;
    __syncthreads();
    long e0 = (long)blockIdx.x * EPB;
    long e1 = e0 + EPB; if (e1 > E) e1 = E;
    for (long e = e0 + threadIdx.x; e < e1; e += ABLK) {
        int r = receivers[e];
        atomicAdd(&hist[r >> LOGNPB], 1);
    }
    __syncthreads();
    int* row = cnt + (long)blockIdx.x * nbuck;
    for (int i = threadIdx.x; i < nbuck; i += ABLK) row[i] = hist[i];
}

// ---------------- pass S1: exclusive scan down each bucket column ----------------
__global__ __launch_bounds__(SBLK) void passS1_colscan(
    int* __restrict__ cnt, int nblk, int nbuck, int* __restrict__ totals)
{
    int b = blockIdx.x;
    int t = threadIdx.x;
    __shared__ int csum[SBLK];
    int per = (nblk + SBLK - 1) / SBLK;
    int i0 = t * per;
    int i1 = i0 + per; if (i1 > nblk) i1 = nblk;
    int s = 0;
    for (int i = i0; i < i1; ++i) s += cnt[(long)i * nbuck + b];
    csum[t] = s;
    __syncthreads();
    for (int off = 1; off < SBLK; off <<= 1) {
        int add = (t >= off) ? csum[t - off] : 0;
        __syncthreads();
        csum[t] += add;
        __syncthreads();
    }
    int run = csum[t] - s;
    for (int i = i0; i < i1; ++i) {
        long a = (long)i * nbuck + b;
        int tmp = cnt[a];
        cnt[a] = run;
        run += tmp;
    }
    if (t == SBLK - 1) totals[b] = csum[SBLK - 1];
}

// ---------------- pass S2: exclusive scan over bucket totals ----------------
__global__ __launch_bounds__(1024) void passS2_basescan(
    const int* __restrict__ totals, int* __restrict__ base, int nbuck)
{
    __shared__ int sh[1024];
    int t = threadIdx.x;
    int v = (t < nbuck) ? totals[t] : 0;
    sh[t] = v;
    __syncthreads();
    for (int off = 1; off < 1024; off <<= 1) {
        int add = (t >= off) ? sh[t - off] : 0;
        __syncthreads();
        sh[t] += add;
        __syncthreads();
    }
    if (t < nbuck) base[t] = sh[t] - v;
}

// ---------------- pass B: scatter edge ids into bucket-sorted order ----------------
__global__ __launch_bounds__(ABLK) void passB_scatter(
    const int* __restrict__ receivers, long E, int nbuck,
    const int* __restrict__ cnt, const int* __restrict__ base,
    unsigned int* __restrict__ sorted)
{
    extern __shared__ int cur[];
    const int* row = cnt + (long)blockIdx.x * nbuck;
    for (int i = threadIdx.x; i < nbuck; i += ABLK) cur[i] = row[i] + base[i];
    __syncthreads();
    long e0 = (long)blockIdx.x * EPB;
    long e1 = e0 + EPB; if (e1 > E) e1 = E;
    for (long e = e0 + threadIdx.x; e < e1; e += ABLK) {
        int r = receivers[e];
        int b = r >> LOGNPB;
        int pos = atomicAdd(&cur[b], 1);
        sorted[pos] = ((unsigned)e << LOGNPB) | (unsigned)(r & (NPB - 1));
    }
}

// ---------------- tier-1 pass C: node sort + gather bf16 messages + SUM ---------
// No weights, no MLP in the gather loop: unpack + 12 adds per edge.
// 2-deep prefetch (18 u32 slots); low VGPR target for 4-5 waves/SIMD.
__global__ __launch_bounds__(CBLK) void passC_sum(
    const unsigned* __restrict__ msg,   // 6 u32 per edge
    const unsigned int* __restrict__ sortedG,
    const int* __restrict__ base, const int* __restrict__ totals,
    float* __restrict__ part,   // null => write out directly
    float* __restrict__ out,
    long total /* N*D */, long slab /* floats per split slab */)
{
    __shared__ int hist[NPB];
    __shared__ int off[NPB + 1];
    __shared__ int cur[NPB];
    __shared__ unsigned sorted2[CAPS];
    __shared__ float facc[NPB * ASTR];

    const int t = threadIdx.x;
    for (int i = t; i < NPB * ASTR; i += CBLK) facc[i] = 0.f;
    if (t < NPB) hist[t] = 0;
    __syncthreads();

    const int b = blockIdx.x;
    const int s = blockIdx.y;
    const int S = gridDim.y;
    const int s0 = base[b];
    const int n  = totals[b];
    const int chunk = (n + S - 1) / S;
    const int g0 = s * chunk;
    int g1 = g0 + chunk; if (g1 > n) g1 = n;
    const int ns = g1 - g0;
    const unsigned* __restrict__ src = sortedG + s0 + g0;

    if (ns > 0 && ns <= CAPS) {
        // phase 1: node histogram over this sub-range
        for (int k = t; k < ns; k += CBLK)
            atomicAdd(&hist[src[k] & (NPB - 1)], 1);
        __syncthreads();

        // phase 2: exclusive scan over NPB counters
        int myh = (t < NPB) ? hist[t] : 0;
        if (t < NPB) off[t] = myh;
        __syncthreads();
        for (int d2 = 1; d2 < NPB; d2 <<= 1) {
            int add = 0;
            if (t < NPB && t >= d2) add = off[t - d2];
            __syncthreads();
            if (t < NPB) off[t] += add;
            __syncthreads();
        }
        if (t < NPB) cur[t] = off[t] - myh;
        __syncthreads();
        if (t < NPB) off[t] = cur[t];
        if (t == 0) off[NPB] = ns;
        __syncthreads();

        // phase 3: scatter edge ids into node-sorted (swizzled) LDS order
        for (int k = t; k < ns; k += CBLK) {
            unsigned e = src[k];
            int pos = atomicAdd(&cur[e & (NPB - 1)], 1);
            sorted2[SWZ(pos)] = e >> LOGNPB;
        }
        __syncthreads();

        // phase 4: 2-deep prefetched gather + SUM into registers
        const int per = (ns + CBLK - 1) / CBLK;
        int k0 = t * per;
        int k1 = k0 + per; if (k1 > ns) k1 = ns;
        if (k0 < k1) {
            int cu = 0;
            while (off[cu + 1] <= k0) ++cu;
            int nodeEnd = off[cu + 1];

            float ac[D];
            #pragma unroll
            for (int j = 0; j < D; ++j) ac[j] = 0.f;

            const int kmax = k1 - 1;
            unsigned iA = sorted2[SWZ(k0)];
            unsigned iB = sorted2[SWZ((k0 + 1 <= kmax) ? k0 + 1 : kmax)];
            const uint2* pA = reinterpret_cast<const uint2*>(msg + (size_t)iA * 6u);
            const uint2* pB = reinterpret_cast<const uint2*>(msg + (size_t)iB * 6u);
            uint2 a0 = pA[0], a1 = pA[1], a2 = pA[2];
            uint2 b0 = pB[0], b1 = pB[1], b2 = pB[2];

            for (int k = k0; k < k1; ++k) {
                int kc = (k + 2 <= kmax) ? k + 2 : kmax;
                unsigned iC = sorted2[SWZ(kc)];
                const uint2* pC = reinterpret_cast<const uint2*>(msg + (size_t)iC * 6u);
                uint2 c0 = pC[0], c1 = pC[1], c2 = pC[2];

                if (k >= nodeEnd) {
                    #pragma unroll
                    for (int j = 0; j < D; ++j) {
                        atomicAdd(&facc[cu * ASTR + j], ac[j]);
                        ac[j] = 0.f;
                    }
                    do { ++cu; } while (off[cu + 1] <= k);
                    nodeEnd = off[cu + 1];
                }
                ac[0]  += bf_lo(a0.x); ac[1]  += bf_hi(a0.x);
                ac[2]  += bf_lo(a0.y); ac[3]  += bf_hi(a0.y);
                ac[4]  += bf_lo(a1.x); ac[5]  += bf_hi(a1.x);
                ac[6]  += bf_lo(a1.y); ac[7]  += bf_hi(a1.y);
                ac[8]  += bf_lo(a2.x); ac[9]  += bf_hi(a2.x);
                ac[10] += bf_lo(a2.y); ac[11] += bf_hi(a2.y);

                a0 = b0; a1 = b1; a2 = b2;
                b0 = c0; b1 = c1; b2 = c2;
            }
            #pragma unroll
            for (int j = 0; j < D; ++j) atomicAdd(&facc[cu * ASTR + j], ac[j]);
        }
    } else if (ns > 0) {
        // oversized sub-range: per-edge LDS atomics (rare)
        for (int k = t; k < ns; k += CBLK) {
            unsigned e = src[k];
            const uint2* rp = reinterpret_cast<const uint2*>(msg + (size_t)(e >> LOGNPB) * 6u);
            uint2 r0 = rp[0], r1 = rp[1], r2 = rp[2];
            int rl = (int)(e & (NPB - 1));
            atomicAdd(&facc[rl * ASTR + 0],  bf_lo(r0.x));
            atomicAdd(&facc[rl * ASTR + 1],  bf_hi(r0.x));
            atomicAdd(&facc[rl * ASTR + 2],  bf_lo(r0.y));
            atomicAdd(&facc[rl * ASTR + 3],  bf_hi(r0.y));
            atomicAdd(&facc[rl * ASTR + 4],  bf_lo(r1.x));
            atomicAdd(&facc[rl * ASTR + 5],  bf_hi(r1.x));
            atomicAdd(&facc[rl * ASTR + 6],  bf_lo(r1.y));
            atomicAdd(&facc[rl * ASTR + 7],  bf_hi(r1.y));
            atomicAdd(&facc[rl * ASTR + 8],  bf_lo(r2.x));
            atomicAdd(&facc[rl * ASTR + 9],  bf_hi(r2.x));
            atomicAdd(&facc[rl * ASTR + 10], bf_lo(r2.y));
            atomicAdd(&facc[rl * ASTR + 11], bf_hi(r2.y));
        }
    }
    __syncthreads();

    if (part != nullptr) {
        float* dst = part + (long)s * slab + (long)b * (NPB * D);
        for (int i = t; i < NPB * D; i += CBLK)
            dst[i] = facc[(i / D) * ASTR + (i % D)];
    } else {
        long obase = (long)b * (NPB * D);
        long cnt_w = total - obase; if (cnt_w > NPB * D) cnt_w = NPB * D;
        for (long i = t; i < cnt_w; i += CBLK)
            out[obase + i] = facc[((int)i / D) * ASTR + ((int)i % D)];
    }
}

// ---------------- reduce: sum SPLIT partial slabs (float4) ----------------
__global__ __launch_bounds__(CBLK) void reduce_partials(
    const float* __restrict__ part, float* __restrict__ out,
    long total4, long slab4, int S)
{
    long i = (long)blockIdx.x * CBLK + threadIdx.x;
    if (i >= total4) return;
    const float4* p = reinterpret_cast<const float4*>(part);
    float4 v = p[i];
    for (int s = 1; s < S; ++s) {
        float4 w = p[(long)s * slab4 + i];
        v.x += w.x; v.y += w.y; v.z += w.z; v.w += w.w;
    }
    reinterpret_cast<float4*>(out)[i] = v;
}

// ---------------- tier-2 pass C: r7 exact (f32 gather + in-loop MLP) -------------
__global__ __launch_bounds__(CBLK) void passC_f32(
    const float* __restrict__ edges,
    const unsigned int* __restrict__ sortedG,
    const int* __restrict__ base, const int* __restrict__ totals,
    const float* __restrict__ bn_scale, const float* __restrict__ bn_bias,
    const float* __restrict__ bn_mean,  const float* __restrict__ bn_var,
    const float* __restrict__ W1, const float* __restrict__ b1,
    const float* __restrict__ W2, const float* __restrict__ b2,
    float* __restrict__ out, long total)
{
    __shared__ float sW1[D * D], sW2[D * D], sB1[D], sB2[D];
    __shared__ int hist[NPB];
    __shared__ int off[NPB + 1];
    __shared__ int cur[NPB];
    __shared__ unsigned sorted2[CAPF];
    __shared__ float facc[NPB * ASTR];

    const int t = threadIdx.x;
    build_weights(t, bn_scale, bn_bias, bn_mean, bn_var, W1, b1, W2, b2,
                  sW1, sW2, sB1, sB2);
    for (int i = t; i < NPB * ASTR; i += CBLK) facc[i] = 0.f;
    if (t < NPB) hist[t] = 0;
    __syncthreads();

    const int b = blockIdx.x;
    const int s0 = base[b];
    const int n  = totals[b];

    if (n <= CAPF) {
        for (int k = t; k < n; k += CBLK)
            atomicAdd(&hist[sortedG[s0 + k] & (NPB - 1)], 1);
        __syncthreads();
        int myh = (t < NPB) ? hist[t] : 0;
        if (t < NPB) off[t] = myh;
        __syncthreads();
        for (int d2 = 1; d2 < NPB; d2 <<= 1) {
            int add = 0;
            if (t < NPB && t >= d2) add = off[t - d2];
            __syncthreads();
            if (t < NPB) off[t] += add;
            __syncthreads();
        }
        if (t < NPB) cur[t] = off[t] - myh;
        __syncthreads();
        if (t < NPB) off[t] = cur[t];
        if (t == 0) off[NPB] = n;
        __syncthreads();
        for (int k = t; k < n; k += CBLK) {
            unsigned e = sortedG[s0 + k];
            int pos = atomicAdd(&cur[e & (NPB - 1)], 1);
            sorted2[SWZ(pos)] = e >> LOGNPB;
        }
        __syncthreads();

        const int per = (n + CBLK - 1) / CBLK;
        int k0 = t * per;
        int k1 = k0 + per; if (k1 > n) k1 = n;
        if (k0 < k1) {
            int cu = 0;
            while (off[cu + 1] <= k0) ++cu;
            int nodeEnd = off[cu + 1];
            float ac[D];
            #pragma unroll
            for (int j = 0; j < D; ++j) ac[j] = 0.f;
            unsigned idx = sorted2[SWZ(k0)];
            const float4* p = reinterpret_cast<const float4*>(edges + (long)idx * D);
            float4 c0 = p[0], c1 = p[1], c2 = p[2];
            for (int k = k0; k < k1; ++k) {
                float4 n0 = c0, n1 = c1, n2 = c2;
                if (k + 1 < k1) {
                    unsigned ix = sorted2[SWZ(k + 1)];
                    const float4* q = reinterpret_cast<const float4*>(edges + (long)ix * D);
                    n0 = q[0]; n1 = q[1]; n2 = q[2];
                }
                if (k >= nodeEnd) {
                    #pragma unroll
                    for (int j = 0; j < D; ++j) {
                        atomicAdd(&facc[cu * ASTR + j], ac[j]);
                        ac[j] = 0.f;
                    }
                    do { ++cu; } while (off[cu + 1] <= k);
                    nodeEnd = off[cu + 1];
                }
                float x[D] = {c0.x, c0.y, c0.z, c0.w, c1.x, c1.y, c1.z, c1.w,
                              c2.x, c2.y, c2.z, c2.w};
                float y[D];
                mlp12(x, sW1, sW2, sB1, sB2, y);
                #pragma unroll
                for (int j = 0; j < D; ++j) ac[j] += y[j];
                c0 = n0; c1 = n1; c2 = n2;
            }
            #pragma unroll
            for (int j = 0; j < D; ++j) atomicAdd(&facc[cu * ASTR + j], ac[j]);
        }
    } else {
        for (int k = t; k < n; k += CBLK) {
            unsigned e = sortedG[s0 + k];
            const float4* p = reinterpret_cast<const float4*>(edges + (long)(e >> LOGNPB) * D);
            float4 c0 = p[0], c1 = p[1], c2 = p[2];
            float x[D] = {c0.x, c0.y, c0.z, c0.w, c1.x, c1.y, c1.z, c1.w,
                          c2.x, c2.y, c2.z, c2.w};
            float y[D];
            mlp12(x, sW1, sW2, sB1, sB2, y);
            int rloc = (int)(e & (NPB - 1));
            #pragma unroll
            for (int j = 0; j < D; ++j) atomicAdd(&facc[rloc * ASTR + j], y[j]);
        }
    }
    __syncthreads();

    long obase = (long)b * (NPB * D);
    long cnt_w = total - obase; if (cnt_w > NPB * D) cnt_w = NPB * D;
    for (long i = t; i < cnt_w; i += CBLK)
        out[obase + i] = facc[((int)i / D) * ASTR + ((int)i % D)];
}

// ---------------- tier-3 fallback: direct atomic scatter ----------------
#define EPT 4
__global__ __launch_bounds__(ABLK) void edge_mlp_scatter(
    const float* __restrict__ edges,
    const float* __restrict__ bn_scale, const float* __restrict__ bn_bias,
    const float* __restrict__ bn_mean,  const float* __restrict__ bn_var,
    const float* __restrict__ W1, const float* __restrict__ b1,
    const float* __restrict__ W2, const float* __restrict__ b2,
    const int* __restrict__ receivers, float* __restrict__ out, long E)
{
    __shared__ float sW1[D * D], sW2[D * D], sB1[D], sB2[D];
    const int t = threadIdx.x;
    build_weights(t, bn_scale, bn_bias, bn_mean, bn_var, W1, b1, W2, b2,
                  sW1, sW2, sB1, sB2);
    __syncthreads();
    const long basee = (long)blockIdx.x * (ABLK * EPT) + t;
    #pragma unroll
    for (int kk = 0; kk < EPT; ++kk) {
        long e = basee + (long)kk * ABLK;
        if (e >= E) continue;
        int r = receivers[e];
        const float4* p = reinterpret_cast<const float4*>(edges + e * D);
        float4 v0 = p[0], v1 = p[1], v2 = p[2];
        float x[D] = {v0.x, v0.y, v0.z, v0.w, v1.x, v1.y, v1.z, v1.w,
                      v2.x, v2.y, v2.z, v2.w};
        float y[D];
        mlp12(x, sW1, sW2, sB1, sB2, y);
        #pragma unroll
        for (int j = 0; j < D; ++j) atomicAdd(&out[(long)r * D + j], y[j]);
    }
}

extern "C" void kernel_launch(void* const* d_in, const int* in_sizes, int n_in,
                              void* d_out, int out_size, void* d_ws, size_t ws_size,
                              hipStream_t stream) {
    const float* edges     = (const float*)d_in[0];
    const float* bn_scale  = (const float*)d_in[1];
    const float* bn_bias   = (const float*)d_in[2];
    const float* bn_mean   = (const float*)d_in[3];
    const float* bn_var    = (const float*)d_in[4];
    const float* W1        = (const float*)d_in[5];
    const float* b1        = (const float*)d_in[6];
    const float* W2        = (const float*)d_in[7];
    const float* b2        = (const float*)d_in[8];
    const int*   receivers = (const int*)d_in[9];
    float*       out       = (float*)d_out;

    const long E = (long)in_sizes[0] / D;
    const int  N = out_size / D;

    const int  nbuck = (N + NPB - 1) >> LOGNPB;
    const long nblk  = (E + EPB - 1) / EPB;
    const size_t cntBytes  = (size_t)nblk * (size_t)nbuck * 4u;
    const size_t head      = cntBytes + 2u * (size_t)nbuck * 4u + 512u;
    const size_t msgBytes  = (size_t)E * 24u;
    const size_t slabBytes = (size_t)nbuck * (size_t)(NPB * D) * 4u;
    const size_t needT1 = head + (size_t)E * 4u + msgBytes + (size_t)SPLIT * slabBytes + 1024u;
    const size_t needT2 = head + (size_t)E * 4u;
    const long total = (long)N * D;

    const bool shapeOK = (nbuck <= 1024) && (E < (1L << 24));
    const size_t lds = (size_t)nbuck * 4u;

    if (shapeOK && ws_size >= needT1) {
        // tier 1: streamed MLP -> bf16 msg, sum-only gather
        char* w = (char*)d_ws;
        int* cnt    = (int*)w;  w += cntBytes;
        int* totals = (int*)w;  w += (size_t)nbuck * 4u;
        int* basep  = (int*)w;  w += (size_t)nbuck * 4u;
        unsigned int* sortedG = (unsigned int*)w;  w += (size_t)E * 4u;
        unsigned* msg = (unsigned*)(((uintptr_t)w + 255u) & ~(uintptr_t)255u);
        w = (char*)msg + msgBytes;
        float* part = (float*)(((uintptr_t)w + 255u) & ~(uintptr_t)255u);

        passA_cvt_mlp <<<dim3((unsigned)nblk), dim3(ABLK), lds, stream>>>(
            receivers, edges, msg, E, nbuck, cnt,
            bn_scale, bn_bias, bn_mean, bn_var, W1, b1, W2, b2);
        passS1_colscan<<<dim3((unsigned)nbuck), dim3(SBLK), 0, stream>>>(cnt, (int)nblk, nbuck, totals);
        passS2_basescan<<<dim3(1), dim3(1024), 0, stream>>>(totals, basep, nbuck);
        passB_scatter <<<dim3((unsigned)nblk), dim3(ABLK), lds, stream>>>(receivers, E, nbuck, cnt, basep, sortedG);

        const long slab = (long)nbuck * (NPB * D);
        passC_sum     <<<dim3((unsigned)nbuck, SPLIT), dim3(CBLK), 0, stream>>>(
            msg, sortedG, basep, totals, part, out, total, slab);
        const long total4 = total / 4;
        const long rblocks = (total4 + CBLK - 1) / CBLK;
        reduce_partials<<<dim3((unsigned)rblocks), dim3(CBLK), 0, stream>>>(
            part, out, total4, slab / 4, SPLIT);
        return;
    }

    if (shapeOK && ws_size >= needT2) {
        // tier 2: r7 exact path
        char* w = (char*)d_ws;
        int* cnt    = (int*)w;  w += cntBytes;
        int* totals = (int*)w;  w += (size_t)nbuck * 4u;
        int* basep  = (int*)w;  w += (size_t)nbuck * 4u;
        unsigned int* sortedG = (unsigned int*)w;

        passA_hist    <<<dim3((unsigned)nblk), dim3(ABLK), lds, stream>>>(receivers, E, nbuck, cnt);
        passS1_colscan<<<dim3((unsigned)nbuck), dim3(SBLK), 0, stream>>>(cnt, (int)nblk, nbuck, totals);
        passS2_basescan<<<dim3(1), dim3(1024), 0, stream>>>(totals, basep, nbuck);
        passB_scatter <<<dim3((unsigned)nblk), dim3(ABLK), lds, stream>>>(receivers, E, nbuck, cnt, basep, sortedG);
        passC_f32     <<<dim3((unsigned)nbuck), dim3(CBLK), 0, stream>>>(
            edges, sortedG, basep, totals,
            bn_scale, bn_bias, bn_mean, bn_var, W1, b1, W2, b2, out, total);
        return;
    }

    (void)hipMemsetAsync(d_out, 0, (size_t)out_size * sizeof(float), stream);
    const long blocks = (E + (long)(ABLK * EPT) - 1) / (long)(ABLK * EPT);
    edge_mlp_scatter<<<dim3((unsigned)blocks), dim3(ABLK), 0, stream>>>(
        edges, bn_scale, bn_bias, bn_mean, bn_var, W1, b1, W2, b2,
        receivers, out, E);
}